// Round 7
// baseline (80.124 us; speedup 1.0000x reference)
//
#include <hip/hip_runtime.h>
#include <hip/hip_bf16.h>

// ShapeletLearner: B=2048, Q=1024, K=32, L=64, S=993
// dist[b,s,l] = wsq[b,s] - (2/K)*cross[b,s,l] + ssq[l];  out = min_s(dist) @ fcw^T + fcb
// R7: 8192 single-wave blocks (b x s-quarter), ZERO barriers (wave-synchronous LDS),
//     wsq from build registers via LDS partial sums (exact fp32), MFMA + DPP max,
//     partial maxima -> d_ws; K2 combines quarters + ssq + FC.

#define B_   2048
#define Q_   1024
#define K_   32
#define L_   64
#define S_   993
#define SQ_  256           // s per quarter
#define XT   288           // tsb row length (max read start 272 + 8, padded)
#define WROW 20            // wsqT row pad

using frag_ab = __attribute__((ext_vector_type(8))) short;   // 8 bf16
using f32x4   = __attribute__((ext_vector_type(4))) float;

static __device__ __forceinline__ unsigned pack_bf16x2(float a, float b) {
    union { __hip_bfloat162 h; unsigned u; } cv;
    cv.h = __float22bfloat162_rn(make_float2(a, b));
    return cv.u;
}

#define DPP_MAX_STEP(v, idf, ctrl)                                               \
    {                                                                            \
        union { float f; int i; } _in, _out;                                     \
        _in.f = v;                                                               \
        _out.i = __builtin_amdgcn_update_dpp(idf, _in.i, ctrl, 0xF, 0xF, false); \
        v = fmaxf(v, _out.f);                                                    \
    }

__global__ __launch_bounds__(64, 4)
void shapelet_k1(const float* __restrict__ ts,
                 const float* __restrict__ shp,
                 float* __restrict__ pmax)          // [8192][64] in d_ws
{
    __shared__ __align__(16) __hip_bfloat16 tsb[8][XT];   // tsb[c][x] = ts[s0+c+x]
    __shared__ float P4[72];                               // sumsq of 4 els
    __shared__ float F3a[72], F3b[72], F3c[72];            // first 3 els of each chunk
    __shared__ __align__(16) float wsqT[16 * WROW];        // [n][j] = -wsq(local i=16j+n)/K

    const int blk  = blockIdx.x;
    const int b    = blk >> 2;
    const int p    = blk & 3;
    const int s0   = SQ_ * p;
    const int lane = threadIdx.x;
    const int n    = lane & 15;
    const int q    = lane >> 4;

    const float* gts = ts + (size_t)b * Q_;

    // ---- build: chunk jj covers tsb[c][4jj..4jj+4) for all 8 c; also P4/F3 ----
    float bv0 = 0.f, bv1 = 0.f, bv2 = 0.f;     // own chunk's first 3 ts values
    #pragma unroll
    for (int pass = 0; pass < 2; ++pass) {
        const int jj = pass == 0 ? lane : 64 + lane;
        if (pass == 1 && lane >= 8) break;
        const int e = s0 + 4 * jj;
        float v[12];
        #pragma unroll
        for (int u = 0; u < 3; ++u) {
            int eu = e + 4 * u;
            eu = eu > (Q_ - 4) ? (Q_ - 4) : eu;
            float4 x = *(const float4*)(gts + eu);
            v[4*u+0] = x.x; v[4*u+1] = x.y; v[4*u+2] = x.z; v[4*u+3] = x.w;
        }
        #pragma unroll
        for (int u = 0; u < 12; ++u)
            if (e + u >= Q_) v[u] = 0.f;
        #pragma unroll
        for (int c = 0; c < 8; ++c)
            *(uint2*)&tsb[c][4 * jj] = make_uint2(pack_bf16x2(v[c+0], v[c+1]),
                                                  pack_bf16x2(v[c+2], v[c+3]));
        P4[jj]  = fmaf(v[0], v[0], fmaf(v[1], v[1], fmaf(v[2], v[2], v[3] * v[3])));
        F3a[jj] = v[0]; F3b[jj] = v[1]; F3c[jj] = v[2];
        if (pass == 0) { bv0 = v[0]; bv1 = v[1]; bv2 = v[2]; }
    }

    // ---- A fragments: shapelets * 2^-4 (exact scale) ----
    frag_ab afrag[4];
    #pragma unroll
    for (int f = 0; f < 4; ++f) {
        const float4* sp = (const float4*)(shp + (f * 16 + n) * K_ + q * 8);
        float4 x0 = sp[0], x1 = sp[1];
        union { frag_ab v; unsigned u[4]; } uu;
        uu.u[0] = pack_bf16x2(x0.x * 0.0625f, x0.y * 0.0625f);
        uu.u[1] = pack_bf16x2(x0.z * 0.0625f, x0.w * 0.0625f);
        uu.u[2] = pack_bf16x2(x1.x * 0.0625f, x1.y * 0.0625f);
        uu.u[3] = pack_bf16x2(x1.z * 0.0625f, x1.w * 0.0625f);
        afrag[f] = uu.v;
    }

    // ---- wsq for this quarter: exact fp32 from P4 + F3 (wave-synchronous LDS) ----
    {
        const int m = lane;                    // s-local = 4m+t
        float p4[8];
        #pragma unroll
        for (int i = 0; i < 8; ++i) p4[i] = P4[m + i];
        const float a0 = F3a[m + 8], a1 = F3b[m + 8], a2 = F3c[m + 8];
        float w0 = ((p4[0] + p4[1]) + (p4[2] + p4[3])) +
                   ((p4[4] + p4[5]) + (p4[6] + p4[7]));
        float w1 = w0 - bv0 * bv0 + a0 * a0;
        float w2 = w1 - bv1 * bv1 + a1 * a1;
        float w3 = w2 - bv2 * bv2 + a2 * a2;
        const int sg = s0 + 4 * m;
        float o0 = (sg + 0 < S_) ? w0 * (-1.0f / K_) : -1e30f;
        float o1 = (sg + 1 < S_) ? w1 * (-1.0f / K_) : -1e30f;
        float o2 = (sg + 2 < S_) ? w2 * (-1.0f / K_) : -1e30f;
        float o3 = (sg + 3 < S_) ? w3 * (-1.0f / K_) : -1e30f;
        // local i = 4m+t -> tile j = m>>2, col n = 4(m&3)+t ; layout wsqT[n][j]
        const int jc = m >> 2, n0 = 4 * (m & 3);
        wsqT[(n0 + 0) * WROW + jc] = o0;
        wsqT[(n0 + 1) * WROW + jc] = o1;
        wsqT[(n0 + 2) * WROW + jc] = o2;
        wsqT[(n0 + 3) * WROW + jc] = o3;
    }

    // ---- preload this lane's 16 (negated) wsq values: 4x ds_read_b128 ----
    float wq[16];
    #pragma unroll
    for (int t = 0; t < 4; ++t) {
        f32x4 x = *(const f32x4*)&wsqT[n * WROW + 4 * t];
        wq[4*t+0] = x[0]; wq[4*t+1] = x[1]; wq[4*t+2] = x[2]; wq[4*t+3] = x[3];
    }

    // ---- main loop: 16 tiles; D = (2/K)*cross - wsq ----
    const __hip_bfloat16* bp = &tsb[n & 7][8 * q + (n & 8)];
    float rm[4][4];
    #pragma unroll
    for (int f = 0; f < 4; ++f)
        #pragma unroll
        for (int r = 0; r < 4; ++r) rm[f][r] = -3e38f;

    #pragma unroll
    for (int j = 0; j < 16; ++j) {
        frag_ab bvf = *(const frag_ab*)(bp + 16 * j);
        const float nw = wq[j];
        f32x4 cin = {nw, nw, nw, nw};
        #pragma unroll
        for (int f = 0; f < 4; ++f) {
            f32x4 d = __builtin_amdgcn_mfma_f32_16x16x32_bf16(afrag[f], bvf, cin, 0, 0, 0);
            #pragma unroll
            for (int r = 0; r < 4; ++r)
                rm[f][r] = fmaxf(rm[f][r], d[r]);
        }
    }

    // ---- max across the 16 s-cols via DPP row scan; lane n==15 holds row max ----
    {
        union { float f; int i; } idc; idc.f = -3e38f;
        const int idf = idc.i;
        #pragma unroll
        for (int f = 0; f < 4; ++f)
            #pragma unroll
            for (int r = 0; r < 4; ++r) {
                float v = rm[f][r];
                DPP_MAX_STEP(v, idf, 0x111);
                DPP_MAX_STEP(v, idf, 0x112);
                DPP_MAX_STEP(v, idf, 0x114);
                DPP_MAX_STEP(v, idf, 0x118);
                rm[f][r] = v;
            }
    }
    if (n == 15) {
        float* dst = pmax + (size_t)blk * 64;
        #pragma unroll
        for (int f = 0; f < 4; ++f) {
            float4 val = make_float4(rm[f][0], rm[f][1], rm[f][2], rm[f][3]);
            *(float4*)(dst + 16 * f + 4 * q) = val;   // l = 16f + 4q + r
        }
    }
}

__global__ __launch_bounds__(64, 4)
void shapelet_k2(const float* __restrict__ shp,
                 const float* __restrict__ fcw,
                 const float* __restrict__ fcb,
                 const float* __restrict__ pmax,
                 float* __restrict__ out)
{
    const int b = blockIdx.x;
    const int l = threadIdx.x;

    const float* pb = pmax + (size_t)b * 4 * 64 + l;
    float y = fmaxf(fmaxf(pb[0], pb[64]), fmaxf(pb[128], pb[192]));

    // ssq[l] exact fp32
    const float* sp = shp + l * K_;
    float s = 0.f;
    #pragma unroll
    for (int k = 0; k < K_; ++k) s = fmaf(sp[k], sp[k], s);
    const float d = s * (1.0f / K_) - y;

    float p0 = d * fcw[l];
    float p1 = d * fcw[L_ + l];
    #pragma unroll
    for (int off = 32; off > 0; off >>= 1) {
        p0 += __shfl_down(p0, off, 64);
        p1 += __shfl_down(p1, off, 64);
    }
    if (l == 0) {
        out[(size_t)b * 2 + 0] = p0 + fcb[0];
        out[(size_t)b * 2 + 1] = p1 + fcb[1];
    }
}

extern "C" void kernel_launch(void* const* d_in, const int* in_sizes, int n_in,
                              void* d_out, int out_size, void* d_ws, size_t ws_size,
                              hipStream_t stream) {
    const float* ts  = (const float*)d_in[0];   // (B, Q) fp32
    const float* shp = (const float*)d_in[1];   // (L, K) fp32
    const float* fcw = (const float*)d_in[2];   // (2, L) fp32
    const float* fcb = (const float*)d_in[3];   // (2,)  fp32
    float* o    = (float*)d_out;                // (B, 2) fp32
    float* pmax = (float*)d_ws;                 // 8192*64 floats = 2 MB

    shapelet_k1<<<B_ * 4, 64, 0, stream>>>(ts, shp, pmax);
    shapelet_k2<<<B_, 64, 0, stream>>>(shp, fcw, fcb, pmax, o);
}

// Round 8
// 79.564 us; speedup vs baseline: 1.0070x; 1.0070x over previous
//
#include <hip/hip_runtime.h>
#include <hip/hip_bf16.h>

// ShapeletLearner: B=2048, Q=1024, K=32, L=64, S=993
// dist[b,s,l] = wsq[b,s] - (2/K)*cross[b,s,l] + ssq[l];  out = min_s(dist) @ fcw^T + fcb
// R8: ONE wave per series (2048 x 64thr), zero barriers, zero second kernel.
//     8 bf16 shift-copies + wsq + 64-tile MFMA loop (paired tiles -> v_max3),
//     DPP max-scan, in-wave FC epilogue. c2k=2^-4 folded into A; -wsq in MFMA C.

#define B_   2048
#define Q_   1024
#define K_   32
#define L_   64
#define S_   993
#define CL   1048          // copy length: max read pos 1040+8
#define WST  68            // wsqT row stride (64 + 4 pad, 16B-aligned rows)

using frag_ab = __attribute__((ext_vector_type(8))) short;   // 8 bf16
using f32x4   = __attribute__((ext_vector_type(4))) float;

static __device__ __forceinline__ unsigned pack_bf16x2(float a, float b) {
    union { __hip_bfloat162 h; unsigned u; } cv;
    cv.h = __float22bfloat162_rn(make_float2(a, b));
    return cv.u;
}

#define DPP_MAX_STEP(v, idf, ctrl)                                               \
    {                                                                            \
        union { float f; int i; } _in, _out;                                     \
        _in.f = v;                                                               \
        _out.i = __builtin_amdgcn_update_dpp(idf, _in.i, ctrl, 0xF, 0xF, false); \
        v = fmaxf(v, _out.f);                                                    \
    }

__global__ __launch_bounds__(64, 2)
void shapelet_one(const float* __restrict__ ts,
                  const float* __restrict__ shp,
                  const float* __restrict__ fcw,
                  const float* __restrict__ fcb,
                  float* __restrict__ out)
{
    __shared__ __align__(16) __hip_bfloat16 tsb[8][CL];   // tsb[c][x] = ts[c+x]
    __shared__ __align__(16) float          wsqT[16 * WST]; // [n][j] = -wsq[16j+n]/K
    __shared__ float                        ymax[L_];

    const int lane = threadIdx.x;
    const int b    = blockIdx.x;
    const int n    = lane & 15;
    const int q    = lane >> 4;
    const float* gts = ts + (size_t)b * Q_;

    // ---- epilogue params (issue loads early) ----
    const float fb0 = fcb[0], fb1 = fcb[1];
    const float fw0 = fcw[lane], fw1 = fcw[L_ + lane];

    // ---- A fragments: shapelets * 2^-4 (exact scale) ----
    frag_ab afrag[4];
    #pragma unroll
    for (int f = 0; f < 4; ++f) {
        const float4* sp = (const float4*)(shp + (f * 16 + n) * K_ + q * 8);
        float4 x0 = sp[0], x1 = sp[1];
        union { frag_ab v; unsigned u[4]; } uu;
        uu.u[0] = pack_bf16x2(x0.x * 0.0625f, x0.y * 0.0625f);
        uu.u[1] = pack_bf16x2(x0.z * 0.0625f, x0.w * 0.0625f);
        uu.u[2] = pack_bf16x2(x1.x * 0.0625f, x1.y * 0.0625f);
        uu.u[3] = pack_bf16x2(x1.z * 0.0625f, x1.w * 0.0625f);
        afrag[f] = uu.v;
    }

    // ---- build 8 shift-copies: passes 0-2 unclamped, pass 3 clamped ----
    #pragma unroll
    for (int p = 0; p < 3; ++p) {
        const int e = 256 * p + 4 * lane;           // dest x = e, needs ts[e .. e+11]
        float v[12];
        #pragma unroll
        for (int u = 0; u < 3; ++u) {
            float4 x = *(const float4*)(gts + e + 4 * u);
            v[4*u+0] = x.x; v[4*u+1] = x.y; v[4*u+2] = x.z; v[4*u+3] = x.w;
        }
        #pragma unroll
        for (int c = 0; c < 8; ++c)
            *(uint2*)&tsb[c][e] = make_uint2(pack_bf16x2(v[c+0], v[c+1]),
                                             pack_bf16x2(v[c+2], v[c+3]));
    }
    {
        const int e = 768 + 4 * lane;               // e in [768,1020]
        float v[12];
        #pragma unroll
        for (int u = 0; u < 3; ++u) {
            int eu = e + 4 * u;
            eu = eu > (Q_ - 4) ? (Q_ - 4) : eu;     // clamp: dup values feed only s>=993 (discarded)
            float4 x = *(const float4*)(gts + eu);
            v[4*u+0] = x.x; v[4*u+1] = x.y; v[4*u+2] = x.z; v[4*u+3] = x.w;
        }
        #pragma unroll
        for (int c = 0; c < 8; ++c)
            *(uint2*)&tsb[c][e] = make_uint2(pack_bf16x2(v[c+0], v[c+1]),
                                             pack_bf16x2(v[c+2], v[c+3]));
        // zero-pad [1024,1048) for all copies (6 uint2 per copy, lanes 0..47)
        if (lane < 48) {
            const int c  = lane / 6;
            const int x0 = Q_ + (lane - 6 * c) * 4;
            *(uint2*)&tsb[c][x0] = make_uint2(0u, 0u);
        }
    }

    // ---- wsq: lane L owns s = 16L .. 16L+15 (tile j = L, col i); store -wsq/K ----
    {
        const int s0 = 16 * lane;
        float vv[48];
        #pragma unroll
        for (int u = 0; u < 12; ++u) {
            int e = s0 + 4 * u;
            e = e > (Q_ - 4) ? (Q_ - 4) : e;        // dup values only reach discarded s>=993
            float4 x = *(const float4*)(gts + e);
            vv[4*u+0] = x.x; vv[4*u+1] = x.y; vv[4*u+2] = x.z; vv[4*u+3] = x.w;
        }
        float w = 0.f;
        #pragma unroll
        for (int k = 0; k < K_; ++k) w = fmaf(vv[k], vv[k], w);
        #pragma unroll
        for (int i = 0; i < 16; ++i) {
            const int s = s0 + i;
            wsqT[i * WST + lane] = (s < S_) ? w * (-1.0f / K_) : -1e30f;
            w = w - vv[i] * vv[i] + vv[32 + i] * vv[32 + i];
        }
    }

    // ---- main loop: 64 s-tiles, paired (8 MFMA in flight, v_max3 reduction) ----
    const __hip_bfloat16* bp = &tsb[n & 7][8 * q + (n & 8)];
    float rm[4][4];
    #pragma unroll
    for (int f = 0; f < 4; ++f)
        #pragma unroll
        for (int r = 0; r < 4; ++r) rm[f][r] = -3e38f;

    #pragma unroll 1
    for (int ch = 0; ch < 4; ++ch) {
        float wq[16];
        #pragma unroll
        for (int t = 0; t < 4; ++t) {
            f32x4 x = *(const f32x4*)&wsqT[n * WST + 16 * ch + 4 * t];
            wq[4*t+0] = x[0]; wq[4*t+1] = x[1]; wq[4*t+2] = x[2]; wq[4*t+3] = x[3];
        }
        const __hip_bfloat16* bpc = bp + 256 * ch;
        #pragma unroll
        for (int jj = 0; jj < 16; jj += 2) {
            frag_ab b0 = *(const frag_ab*)(bpc + 16 * jj);
            frag_ab b1 = *(const frag_ab*)(bpc + 16 * jj + 16);
            const float nw0 = wq[jj], nw1 = wq[jj + 1];
            f32x4 c0 = {nw0, nw0, nw0, nw0};
            f32x4 c1 = {nw1, nw1, nw1, nw1};
            #pragma unroll
            for (int f = 0; f < 4; ++f) {
                f32x4 d0 = __builtin_amdgcn_mfma_f32_16x16x32_bf16(afrag[f], b0, c0, 0, 0, 0);
                f32x4 d1 = __builtin_amdgcn_mfma_f32_16x16x32_bf16(afrag[f], b1, c1, 0, 0, 0);
                #pragma unroll
                for (int r = 0; r < 4; ++r)
                    rm[f][r] = fmaxf(fmaxf(rm[f][r], d0[r]), d1[r]);   // v_max3
            }
        }
    }

    // ---- max across the 16 s-cols (DPP row scan); lane n==15 holds row max ----
    {
        union { float f; int i; } idc; idc.f = -3e38f;
        const int idf = idc.i;
        #pragma unroll
        for (int f = 0; f < 4; ++f)
            #pragma unroll
            for (int r = 0; r < 4; ++r) {
                float v = rm[f][r];
                DPP_MAX_STEP(v, idf, 0x111);
                DPP_MAX_STEP(v, idf, 0x112);
                DPP_MAX_STEP(v, idf, 0x114);
                DPP_MAX_STEP(v, idf, 0x118);
                rm[f][r] = v;
            }
    }
    if (n == 15) {
        #pragma unroll
        for (int f = 0; f < 4; ++f)
            #pragma unroll
            for (int r = 0; r < 4; ++r)
                ymax[16 * f + 4 * q + r] = rm[f][r];   // l = 16f + 4q + r
    }

    // ---- in-wave FC epilogue: d[l] = ssq[l] - y[l]; out = d @ fcw^T + fcb ----
    {
        const float y = ymax[lane];
        const float4* sp = (const float4*)(shp + lane * K_);
        float s = 0.f;
        #pragma unroll
        for (int u = 0; u < 8; ++u) {
            float4 x = sp[u];
            s = fmaf(x.x, x.x, s); s = fmaf(x.y, x.y, s);
            s = fmaf(x.z, x.z, s); s = fmaf(x.w, x.w, s);
        }
        const float d = s * (1.0f / K_) - y;
        float p0 = d * fw0;
        float p1 = d * fw1;
        #pragma unroll
        for (int off = 32; off > 0; off >>= 1) {
            p0 += __shfl_down(p0, off, 64);
            p1 += __shfl_down(p1, off, 64);
        }
        if (lane == 0) {
            float2 o = make_float2(p0 + fb0, p1 + fb1);
            *(float2*)(out + (size_t)b * 2) = o;
        }
    }
}

extern "C" void kernel_launch(void* const* d_in, const int* in_sizes, int n_in,
                              void* d_out, int out_size, void* d_ws, size_t ws_size,
                              hipStream_t stream) {
    const float* ts  = (const float*)d_in[0];   // (B, Q) fp32
    const float* shp = (const float*)d_in[1];   // (L, K) fp32
    const float* fcw = (const float*)d_in[2];   // (2, L) fp32
    const float* fcb = (const float*)d_in[3];   // (2,)  fp32
    float* o = (float*)d_out;                   // (B, 2) fp32

    shapelet_one<<<B_, 64, 0, stream>>>(ts, shp, fcw, fcb, o);
}